// Round 2
// baseline (247.764 us; speedup 1.0000x reference)
//
#include <hip/hip_runtime.h>
#include <stdint.h>

// ---------------------------------------------------------------------------
// Threefry-2x32, 20 rounds — bit-exact match of JAX's threefry2x32 primitive.
// Host-side key derivation + device single-chain (pos-mask draws).
// ---------------------------------------------------------------------------
#define TF_ROUND(x0, x1, r)                    \
  {                                            \
    x0 += x1;                                  \
    x1 = (x1 << (r)) | (x1 >> (32 - (r)));     \
    x1 ^= x0;                                  \
  }

__host__ __device__ inline void threefry2x32(uint32_t k0, uint32_t k1,
                                             uint32_t x0, uint32_t x1,
                                             uint32_t& o0, uint32_t& o1) {
  const uint32_t ks2 = k0 ^ k1 ^ 0x1BD11BDAu;
  x0 += k0; x1 += k1;
  TF_ROUND(x0, x1, 13) TF_ROUND(x0, x1, 15) TF_ROUND(x0, x1, 26) TF_ROUND(x0, x1, 6)
  x0 += k1; x1 += ks2 + 1u;
  TF_ROUND(x0, x1, 17) TF_ROUND(x0, x1, 29) TF_ROUND(x0, x1, 16) TF_ROUND(x0, x1, 24)
  x0 += ks2; x1 += k0 + 2u;
  TF_ROUND(x0, x1, 13) TF_ROUND(x0, x1, 15) TF_ROUND(x0, x1, 26) TF_ROUND(x0, x1, 6)
  x0 += k0; x1 += k1 + 3u;
  TF_ROUND(x0, x1, 17) TF_ROUND(x0, x1, 29) TF_ROUND(x0, x1, 16) TF_ROUND(x0, x1, 24)
  x0 += k1; x1 += ks2 + 4u;
  TF_ROUND(x0, x1, 13) TF_ROUND(x0, x1, 15) TF_ROUND(x0, x1, 26) TF_ROUND(x0, x1, 6)
  x0 += ks2; x1 += k0 + 5u;
  o0 = x0; o1 = x1;
}

// ---------------------------------------------------------------------------
// 4-wide lockstep threefry: alignbit rotates, injection fused into the first
// round of each stage (x1+=B; x0=x0+A+x1 -> v_add3 form). All reassociations
// are mod-2^32 exact -> bit-identical to the reference chain. ~68 VALU/elem.
// ---------------------------------------------------------------------------
#define RND4(r)                                                     \
  _Pragma("unroll") for (int e = 0; e < 4; ++e) {                   \
    x0[e] += x1[e];                                                 \
    x1[e] = __builtin_amdgcn_alignbit(x1[e], x1[e], 32u - (r));     \
    x1[e] ^= x0[e];                                                 \
  }
// inject (x0+=A; x1+=B) fused with the following round's x0+=x1:
#define FUSED4(A, Bc, r)                                            \
  _Pragma("unroll") for (int e = 0; e < 4; ++e) {                   \
    x1[e] += (Bc);                                                  \
    x0[e] = x0[e] + (A) + x1[e];                                    \
    x1[e] = __builtin_amdgcn_alignbit(x1[e], x1[e], 32u - (r));     \
    x1[e] ^= x0[e];                                                 \
  }

// tbk = row_base + lane*4 + k1 (counter + k1 pre-folded); lit = chunk offset.
__device__ __forceinline__ void tf4(uint32_t k0, uint32_t k1, uint32_t ks2,
                                    uint32_t tbk, uint32_t lit, uint32_t* o) {
  uint32_t x0[4], x1[4];
  // Round 1 with init folded: x0 = k0 + x1_init (saves the mov + separate add).
#pragma unroll
  for (int e = 0; e < 4; ++e) {
    x1[e] = tbk + (lit + (uint32_t)e);
    x0[e] = k0 + x1[e];
    x1[e] = __builtin_amdgcn_alignbit(x1[e], x1[e], 32u - 13u);
    x1[e] ^= x0[e];
  }
  RND4(15) RND4(26) RND4(6)
  FUSED4(k1, ks2 + 1u, 17)
  RND4(29) RND4(16) RND4(24)
  FUSED4(ks2, k0 + 2u, 13)
  RND4(15) RND4(26) RND4(6)
  FUSED4(k0, k1 + 3u, 17)
  RND4(29) RND4(16) RND4(24)
  FUSED4(k1, ks2 + 4u, 13)
  RND4(15) RND4(26) RND4(6)
#pragma unroll
  for (int e = 0; e < 4; ++e) o[e] = (x0[e] + ks2) ^ (x1[e] + (k0 + 5u));
}

// ---------------------------------------------------------------------------
// Problem constants.
// ---------------------------------------------------------------------------
constexpr int B = 16;
constexpr int N = 1024;
constexpr int G = 2000;
constexpr int NUM_ROWS = B * N;                      // 16384
constexpr uint32_t RANK = (uint32_t)(G - 800 - 1);   // 1199 (0-based kth index)
constexpr long long EXPR_ELEMS = (long long)NUM_ROWS * G;
constexpr int ROWS_PER_BLOCK = 4;                    // one wave per row

typedef int v4i __attribute__((ext_vector_type(4)));

// ---------------------------------------------------------------------------
// One WAVE per row, 4 rows/block, ZERO block barriers, and — new this round —
// ZERO per-element LDS traffic. Selection is radix bisection via __ballot:
//   phase 1: 7 uniform-threshold sweeps over the 32 register slots count
//            elements below trial via v_cmp -> s_bcnt1 (SALU rides the free
//            issue slot) -> 7-bit bucket B and count-below cb. No LDS.
//   phase 2: ~16 candidates (Poisson(15.6); P(>64) ~ 1e-18) appended to a
//            64-entry per-wave LDS buffer (~16 DS ops/row vs 2000 before),
//            then 16 more ballot-bisect steps pin the low 16 bits of the
//            rank-1199 value. Threshold lands in an SGPR; no broadcast.
// Mask write: o >= (T<<9)  (monotone-equivalent to f32 uniform >= kth).
// ---------------------------------------------------------------------------
__global__ __launch_bounds__(256) void fused_mask_kernel(
    int32_t* __restrict__ out_expr, int32_t* __restrict__ out_pos,
    uint32_t ke0, uint32_t ke1,
    uint32_t kr0, uint32_t kr1,
    uint32_t ah0, uint32_t ah1, uint32_t al0, uint32_t al1,
    uint32_t bh0, uint32_t bh1, uint32_t bl0, uint32_t bl1) {
  __shared__ uint32_t cand[ROWS_PER_BLOCK][64];
  __shared__ uint32_t cnt[ROWS_PER_BLOCK];

  const int t = threadIdx.x;
  const int lane = t & 63;
  const int w = t >> 6;
  const uint32_t row = blockIdx.x * (uint32_t)ROWS_PER_BLOCK + (uint32_t)w;
  const uint32_t rbase = row * (uint32_t)G;

  if (lane == 0) cnt[w] = 0u;

  const uint32_t ks2 = ke0 ^ ke1 ^ 0x1BD11BDAu;
  const uint32_t tbk = rbase + (uint32_t)(lane << 2) + ke1;

  uint32_t o[32];
  uint32_t pb = 0u;

  // --- Generation: 7 full chunks of 4 contiguous elements per lane.
#pragma unroll
  for (int j = 0; j < 7; ++j) {
    tf4(ke0, ke1, ks2, tbk, (uint32_t)(j * 256), &o[j * 4]);
  }
  // --- Partial chunk: lanes 0..51 cover elements 1792..1999; lanes 52..56
  // --- compute the 5 pos-mask threefry draws in the shadow.
  if (lane < 52) {
    tf4(ke0, ke1, ks2, tbk, 1792u, &o[28]);
  } else {
#pragma unroll
    for (int e = 0; e < 4; ++e) o[28 + e] = 0xFFFFFFFFu;  // never < any trial
    if (lane < 57) {
      uint32_t pk0, pk1;
      switch (lane) {
        case 52: pk0 = kr0; pk1 = kr1; break;
        case 53: pk0 = ah0; pk1 = ah1; break;
        case 54: pk0 = al0; pk1 = al1; break;
        case 55: pk0 = bh0; pk1 = bh1; break;
        default: pk0 = bl0; pk1 = bl1; break;
      }
      uint32_t y0, y1;
      threefry2x32(pk0, pk1, 0u, row, y0, y1);
      pb = y0 ^ y1;
    }
  }

  // --- Phase 1: 7-bit radix bisect (m-space bits 22..16 == o-space 31..25).
  // cnt(m < Bv<<16) == cnt(o < Bv<<25); sentinels (0xFFFFFFFF) never counted
  // since max trial is 127<<25 = 0xFE000000. Uniform control flow throughout.
  uint32_t Bv = 0u, cb = 0u;
#pragma unroll
  for (int bit = 6; bit >= 0; --bit) {
    const uint32_t sthr = (Bv | (1u << bit)) << 25;
    uint32_t c = 0u;
#pragma unroll
    for (int i = 0; i < 32; ++i)
      c += (uint32_t)__builtin_popcountll(__ballot(o[i] < sthr));
    if (c <= RANK) { Bv |= (1u << bit); cb = c; }   // uniform (SALU cselect)
  }

  // --- Phase 2a: collect this bucket's candidates into per-wave LDS.
#pragma unroll
  for (int i = 0; i < 28; ++i) {
    if ((o[i] >> 25) == Bv) {
      uint32_t p = atomicAdd(&cnt[w], 1u);
      if (p < 64u) cand[w][p] = o[i] >> 9;   // 23-bit m value
    }
  }
  if (lane < 52) {
#pragma unroll
    for (int i = 28; i < 32; ++i) {
      if ((o[i] >> 25) == Bv) {
        uint32_t p = atomicAdd(&cnt[w], 1u);
        if (p < 64u) cand[w][p] = o[i] >> 9;
      }
    }
  }
  __builtin_amdgcn_wave_barrier();  // same-wave DS ordering fence

  // --- Phase 2b: bisect low 16 bits among candidates (value-select is
  // tie-break invariant; kk = rank within bucket).
  uint32_t c = cnt[w];
  if (c > 64u) c = 64u;
  const uint32_t myc = ((uint32_t)lane < c) ? cand[w][lane] : 0xFFFFFFFFu;
  const uint32_t kk = RANK - cb;
  uint32_t T = Bv << 16;
#pragma unroll
  for (int bit = 15; bit >= 0; --bit) {
    const uint32_t trial = T | (1u << bit);
    const uint32_t cc = (uint32_t)__builtin_popcountll(__ballot(myc < trial));
    if (cc <= kk) T = trial;                        // uniform (SALU)
  }
  const uint32_t sT9 = T << 9;   // threshold in o-space (low 9 bits zero)

  // --- Pos-mask combine (bit-exact verified logic; lanes 0..2 store).
  {
    uint32_t p0 = (uint32_t)__shfl((int)pb, 52, 64);
    uint32_t p1 = (uint32_t)__shfl((int)pb, 53, 64);
    uint32_t p2 = (uint32_t)__shfl((int)pb, 54, 64);
    uint32_t p3 = (uint32_t)__shfl((int)pb, 55, 64);
    uint32_t p4 = (uint32_t)__shfl((int)pb, 56, 64);
    if (lane < 3) {
      union { uint32_t u; float f; } cvt;
      cvt.u = (p0 >> 9) | 0x3F800000u;
      float rr = cvt.f - 1.0f;
      const float THR2 = (float)(0.33 * 0.3);
      const float THR1 = (float)0.33;
      bool two = rr < THR2;
      bool one = (rr < THR1) && !two;
      int dim1 = (int)(((p1 % 3u) + (p2 % 3u)) % 3u);
      int excl = (int)(((p3 % 3u) + (p4 % 3u)) % 3u);
      bool mval = two ? (lane != excl) : (one ? (lane == dim1) : false);
      out_pos[row * 3u + (uint32_t)lane] = mval ? 1 : 0;
    }
  }

  // --- Streaming stores: mask = (o >= T<<9), nontemporal dwordx4.
  int32_t* op = out_expr + rbase + (uint32_t)(lane << 2);
#pragma unroll
  for (int j = 0; j < 7; ++j) {
    v4i a;
    a.x = (o[j * 4 + 0] >= sT9) ? 1 : 0;
    a.y = (o[j * 4 + 1] >= sT9) ? 1 : 0;
    a.z = (o[j * 4 + 2] >= sT9) ? 1 : 0;
    a.w = (o[j * 4 + 3] >= sT9) ? 1 : 0;
    __builtin_nontemporal_store(a, (v4i*)(op + j * 256));
  }
  if (lane < 52) {
    v4i a;
    a.x = (o[28] >= sT9) ? 1 : 0;
    a.y = (o[29] >= sT9) ? 1 : 0;
    a.z = (o[30] >= sT9) ? 1 : 0;
    a.w = (o[31] >= sT9) ? 1 : 0;
    __builtin_nontemporal_store(a, (v4i*)(op + 1792));
  }
}

// ---------------------------------------------------------------------------
// Launch
// ---------------------------------------------------------------------------
extern "C" void kernel_launch(void* const* d_in, const int* in_sizes, int n_in,
                              void* d_out, int out_size, void* d_ws, size_t ws_size,
                              hipStream_t stream) {
  (void)d_in; (void)in_sizes; (void)n_in; (void)d_ws; (void)ws_size; (void)out_size;

  // Host-side key derivation (partitionable fold-like split — verified):
  //   base = key(42) = (0, 42)
  //   ke, kp   = split(base)    -> TF(base,(0,0)), TF(base,(0,1))
  //   kr,k1,k2 = split(kp, 3)   -> TF(kp,(0,j)), j=0..2
  //   randint internal: split(k1) -> ah,al ; split(k2) -> bh,bl
  uint32_t ke0, ke1, kp0, kp1;
  threefry2x32(0u, 42u, 0u, 0u, ke0, ke1);
  threefry2x32(0u, 42u, 0u, 1u, kp0, kp1);
  uint32_t kr0, kr1, ka0, ka1, kb0, kb1;
  threefry2x32(kp0, kp1, 0u, 0u, kr0, kr1);
  threefry2x32(kp0, kp1, 0u, 1u, ka0, ka1);
  threefry2x32(kp0, kp1, 0u, 2u, kb0, kb1);
  uint32_t ah0, ah1, al0, al1, bh0, bh1, bl0, bl1;
  threefry2x32(ka0, ka1, 0u, 0u, ah0, ah1);
  threefry2x32(ka0, ka1, 0u, 1u, al0, al1);
  threefry2x32(kb0, kb1, 0u, 0u, bh0, bh1);
  threefry2x32(kb0, kb1, 0u, 1u, bl0, bl1);

  int32_t* out_expr = (int32_t*)d_out;
  int32_t* out_pos = out_expr + EXPR_ELEMS;

  fused_mask_kernel<<<NUM_ROWS / ROWS_PER_BLOCK, 256, 0, stream>>>(
      out_expr, out_pos, ke0, ke1, kr0, kr1,
      ah0, ah1, al0, al1, bh0, bh1, bl0, bl1);
}

// Round 3
// 246.738 us; speedup vs baseline: 1.0042x; 1.0042x over previous
//
#include <hip/hip_runtime.h>
#include <stdint.h>

// ---------------------------------------------------------------------------
// Threefry-2x32, 20 rounds — bit-exact match of JAX's threefry2x32 primitive.
// Host-side key derivation + device single-chain (pos-mask draws).
// ---------------------------------------------------------------------------
#define TF_ROUND(x0, x1, r)                    \
  {                                            \
    x0 += x1;                                  \
    x1 = (x1 << (r)) | (x1 >> (32 - (r)));     \
    x1 ^= x0;                                  \
  }

__host__ __device__ inline void threefry2x32(uint32_t k0, uint32_t k1,
                                             uint32_t x0, uint32_t x1,
                                             uint32_t& o0, uint32_t& o1) {
  const uint32_t ks2 = k0 ^ k1 ^ 0x1BD11BDAu;
  x0 += k0; x1 += k1;
  TF_ROUND(x0, x1, 13) TF_ROUND(x0, x1, 15) TF_ROUND(x0, x1, 26) TF_ROUND(x0, x1, 6)
  x0 += k1; x1 += ks2 + 1u;
  TF_ROUND(x0, x1, 17) TF_ROUND(x0, x1, 29) TF_ROUND(x0, x1, 16) TF_ROUND(x0, x1, 24)
  x0 += ks2; x1 += k0 + 2u;
  TF_ROUND(x0, x1, 13) TF_ROUND(x0, x1, 15) TF_ROUND(x0, x1, 26) TF_ROUND(x0, x1, 6)
  x0 += k0; x1 += k1 + 3u;
  TF_ROUND(x0, x1, 17) TF_ROUND(x0, x1, 29) TF_ROUND(x0, x1, 16) TF_ROUND(x0, x1, 24)
  x0 += k1; x1 += ks2 + 4u;
  TF_ROUND(x0, x1, 13) TF_ROUND(x0, x1, 15) TF_ROUND(x0, x1, 26) TF_ROUND(x0, x1, 6)
  x0 += ks2; x1 += k0 + 5u;
  o0 = x0; o1 = x1;
}

// ---------------------------------------------------------------------------
// 4-wide lockstep threefry: alignbit rotates, injection fused into the first
// round of each stage (x1+=B; x0=x0+A+x1 -> v_add3 form). All reassociations
// are mod-2^32 exact -> bit-identical to the reference chain. ~68 VALU/elem.
// ---------------------------------------------------------------------------
#define RND4(r)                                                     \
  _Pragma("unroll") for (int e = 0; e < 4; ++e) {                   \
    x0[e] += x1[e];                                                 \
    x1[e] = __builtin_amdgcn_alignbit(x1[e], x1[e], 32u - (r));     \
    x1[e] ^= x0[e];                                                 \
  }
// inject (x0+=A; x1+=B) fused with the following round's x0+=x1:
#define FUSED4(A, Bc, r)                                            \
  _Pragma("unroll") for (int e = 0; e < 4; ++e) {                   \
    x1[e] += (Bc);                                                  \
    x0[e] = x0[e] + (A) + x1[e];                                    \
    x1[e] = __builtin_amdgcn_alignbit(x1[e], x1[e], 32u - (r));     \
    x1[e] ^= x0[e];                                                 \
  }

// tbk = row_base + lane*4 + k1 (counter + k1 pre-folded); lit = chunk offset.
__device__ __forceinline__ void tf4(uint32_t k0, uint32_t k1, uint32_t ks2,
                                    uint32_t tbk, uint32_t lit, uint32_t* o) {
  uint32_t x0[4], x1[4];
  // Round 1 with init folded: x0 = k0 + x1_init (saves the mov + separate add).
#pragma unroll
  for (int e = 0; e < 4; ++e) {
    x1[e] = tbk + (lit + (uint32_t)e);
    x0[e] = k0 + x1[e];
    x1[e] = __builtin_amdgcn_alignbit(x1[e], x1[e], 32u - 13u);
    x1[e] ^= x0[e];
  }
  RND4(15) RND4(26) RND4(6)
  FUSED4(k1, ks2 + 1u, 17)
  RND4(29) RND4(16) RND4(24)
  FUSED4(ks2, k0 + 2u, 13)
  RND4(15) RND4(26) RND4(6)
  FUSED4(k0, k1 + 3u, 17)
  RND4(29) RND4(16) RND4(24)
  FUSED4(k1, ks2 + 4u, 13)
  RND4(15) RND4(26) RND4(6)
#pragma unroll
  for (int e = 0; e < 4; ++e) o[e] = (x0[e] + ks2) ^ (x1[e] + (k0 + 5u));
}

// ---------------------------------------------------------------------------
// Problem constants.
// ---------------------------------------------------------------------------
constexpr int B = 16;
constexpr int N = 1024;
constexpr int G = 2000;
constexpr int NUM_ROWS = B * N;                      // 16384
constexpr uint32_t RANK = (uint32_t)(G - 800 - 1);   // 1199 (0-based kth index)
constexpr long long EXPR_ELEMS = (long long)NUM_ROWS * G;
constexpr int ROWS_PER_BLOCK = 4;                    // one wave per row

typedef int v4i __attribute__((ext_vector_type(4)));

// ---------------------------------------------------------------------------
// Identical to Round 2 EXCEPT: all stores are PLAIN (cached) instead of
// nontemporal. Theory under test: the nt/streaming store path caps at
// ~1.65 TB/s on gfx950 (three structurally different kernels all pinned at
// exactly 131 MB / 80 µs, while fillBufferAligned with cached stores does
// 6.5 TB/s in the same capture). Single-variable A/B.
// ---------------------------------------------------------------------------
__global__ __launch_bounds__(256) void fused_mask_kernel(
    int32_t* __restrict__ out_expr, int32_t* __restrict__ out_pos,
    uint32_t ke0, uint32_t ke1,
    uint32_t kr0, uint32_t kr1,
    uint32_t ah0, uint32_t ah1, uint32_t al0, uint32_t al1,
    uint32_t bh0, uint32_t bh1, uint32_t bl0, uint32_t bl1) {
  __shared__ uint32_t cand[ROWS_PER_BLOCK][64];
  __shared__ uint32_t cnt[ROWS_PER_BLOCK];

  const int t = threadIdx.x;
  const int lane = t & 63;
  const int w = t >> 6;
  const uint32_t row = blockIdx.x * (uint32_t)ROWS_PER_BLOCK + (uint32_t)w;
  const uint32_t rbase = row * (uint32_t)G;

  if (lane == 0) cnt[w] = 0u;

  const uint32_t ks2 = ke0 ^ ke1 ^ 0x1BD11BDAu;
  const uint32_t tbk = rbase + (uint32_t)(lane << 2) + ke1;

  uint32_t o[32];
  uint32_t pb = 0u;

  // --- Generation: 7 full chunks of 4 contiguous elements per lane.
#pragma unroll
  for (int j = 0; j < 7; ++j) {
    tf4(ke0, ke1, ks2, tbk, (uint32_t)(j * 256), &o[j * 4]);
  }
  // --- Partial chunk: lanes 0..51 cover elements 1792..1999; lanes 52..56
  // --- compute the 5 pos-mask threefry draws in the shadow.
  if (lane < 52) {
    tf4(ke0, ke1, ks2, tbk, 1792u, &o[28]);
  } else {
#pragma unroll
    for (int e = 0; e < 4; ++e) o[28 + e] = 0xFFFFFFFFu;  // never < any trial
    if (lane < 57) {
      uint32_t pk0, pk1;
      switch (lane) {
        case 52: pk0 = kr0; pk1 = kr1; break;
        case 53: pk0 = ah0; pk1 = ah1; break;
        case 54: pk0 = al0; pk1 = al1; break;
        case 55: pk0 = bh0; pk1 = bh1; break;
        default: pk0 = bl0; pk1 = bl1; break;
      }
      uint32_t y0, y1;
      threefry2x32(pk0, pk1, 0u, row, y0, y1);
      pb = y0 ^ y1;
    }
  }

  // --- Phase 1: 7-bit radix bisect (m-space bits 22..16 == o-space 31..25).
  // cnt(m < Bv<<16) == cnt(o < Bv<<25); sentinels (0xFFFFFFFF) never counted
  // since max trial is 127<<25 = 0xFE000000. Uniform control flow throughout.
  uint32_t Bv = 0u, cb = 0u;
#pragma unroll
  for (int bit = 6; bit >= 0; --bit) {
    const uint32_t sthr = (Bv | (1u << bit)) << 25;
    uint32_t c = 0u;
#pragma unroll
    for (int i = 0; i < 32; ++i)
      c += (uint32_t)__builtin_popcountll(__ballot(o[i] < sthr));
    if (c <= RANK) { Bv |= (1u << bit); cb = c; }   // uniform (SALU cselect)
  }

  // --- Phase 2a: collect this bucket's candidates into per-wave LDS.
#pragma unroll
  for (int i = 0; i < 28; ++i) {
    if ((o[i] >> 25) == Bv) {
      uint32_t p = atomicAdd(&cnt[w], 1u);
      if (p < 64u) cand[w][p] = o[i] >> 9;   // 23-bit m value
    }
  }
  if (lane < 52) {
#pragma unroll
    for (int i = 28; i < 32; ++i) {
      if ((o[i] >> 25) == Bv) {
        uint32_t p = atomicAdd(&cnt[w], 1u);
        if (p < 64u) cand[w][p] = o[i] >> 9;
      }
    }
  }
  __builtin_amdgcn_wave_barrier();  // same-wave DS ordering fence

  // --- Phase 2b: bisect low 16 bits among candidates (value-select is
  // tie-break invariant; kk = rank within bucket).
  uint32_t c = cnt[w];
  if (c > 64u) c = 64u;
  const uint32_t myc = ((uint32_t)lane < c) ? cand[w][lane] : 0xFFFFFFFFu;
  const uint32_t kk = RANK - cb;
  uint32_t T = Bv << 16;
#pragma unroll
  for (int bit = 15; bit >= 0; --bit) {
    const uint32_t trial = T | (1u << bit);
    const uint32_t cc = (uint32_t)__builtin_popcountll(__ballot(myc < trial));
    if (cc <= kk) T = trial;                        // uniform (SALU)
  }
  const uint32_t sT9 = T << 9;   // threshold in o-space (low 9 bits zero)

  // --- Pos-mask combine (bit-exact verified logic; lanes 0..2 store).
  {
    uint32_t p0 = (uint32_t)__shfl((int)pb, 52, 64);
    uint32_t p1 = (uint32_t)__shfl((int)pb, 53, 64);
    uint32_t p2 = (uint32_t)__shfl((int)pb, 54, 64);
    uint32_t p3 = (uint32_t)__shfl((int)pb, 55, 64);
    uint32_t p4 = (uint32_t)__shfl((int)pb, 56, 64);
    if (lane < 3) {
      union { uint32_t u; float f; } cvt;
      cvt.u = (p0 >> 9) | 0x3F800000u;
      float rr = cvt.f - 1.0f;
      const float THR2 = (float)(0.33 * 0.3);
      const float THR1 = (float)0.33;
      bool two = rr < THR2;
      bool one = (rr < THR1) && !two;
      int dim1 = (int)(((p1 % 3u) + (p2 % 3u)) % 3u);
      int excl = (int)(((p3 % 3u) + (p4 % 3u)) % 3u);
      bool mval = two ? (lane != excl) : (one ? (lane == dim1) : false);
      out_pos[row * 3u + (uint32_t)lane] = mval ? 1 : 0;
    }
  }

  // --- Streaming stores: mask = (o >= T<<9), PLAIN cached dwordx4 stores.
  int32_t* op = out_expr + rbase + (uint32_t)(lane << 2);
#pragma unroll
  for (int j = 0; j < 7; ++j) {
    v4i a;
    a.x = (o[j * 4 + 0] >= sT9) ? 1 : 0;
    a.y = (o[j * 4 + 1] >= sT9) ? 1 : 0;
    a.z = (o[j * 4 + 2] >= sT9) ? 1 : 0;
    a.w = (o[j * 4 + 3] >= sT9) ? 1 : 0;
    *(v4i*)(op + j * 256) = a;
  }
  if (lane < 52) {
    v4i a;
    a.x = (o[28] >= sT9) ? 1 : 0;
    a.y = (o[29] >= sT9) ? 1 : 0;
    a.z = (o[30] >= sT9) ? 1 : 0;
    a.w = (o[31] >= sT9) ? 1 : 0;
    *(v4i*)(op + 1792) = a;
  }
}

// ---------------------------------------------------------------------------
// Launch
// ---------------------------------------------------------------------------
extern "C" void kernel_launch(void* const* d_in, const int* in_sizes, int n_in,
                              void* d_out, int out_size, void* d_ws, size_t ws_size,
                              hipStream_t stream) {
  (void)d_in; (void)in_sizes; (void)n_in; (void)d_ws; (void)ws_size; (void)out_size;

  // Host-side key derivation (partitionable fold-like split — verified):
  //   base = key(42) = (0, 42)
  //   ke, kp   = split(base)    -> TF(base,(0,0)), TF(base,(0,1))
  //   kr,k1,k2 = split(kp, 3)   -> TF(kp,(0,j)), j=0..2
  //   randint internal: split(k1) -> ah,al ; split(k2) -> bh,bl
  uint32_t ke0, ke1, kp0, kp1;
  threefry2x32(0u, 42u, 0u, 0u, ke0, ke1);
  threefry2x32(0u, 42u, 0u, 1u, kp0, kp1);
  uint32_t kr0, kr1, ka0, ka1, kb0, kb1;
  threefry2x32(kp0, kp1, 0u, 0u, kr0, kr1);
  threefry2x32(kp0, kp1, 0u, 1u, ka0, ka1);
  threefry2x32(kp0, kp1, 0u, 2u, kb0, kb1);
  uint32_t ah0, ah1, al0, al1, bh0, bh1, bl0, bl1;
  threefry2x32(ka0, ka1, 0u, 0u, ah0, ah1);
  threefry2x32(ka0, ka1, 0u, 1u, al0, al1);
  threefry2x32(kb0, kb1, 0u, 0u, bh0, bh1);
  threefry2x32(kb0, kb1, 0u, 1u, bl0, bl1);

  int32_t* out_expr = (int32_t*)d_out;
  int32_t* out_pos = out_expr + EXPR_ELEMS;

  fused_mask_kernel<<<NUM_ROWS / ROWS_PER_BLOCK, 256, 0, stream>>>(
      out_expr, out_pos, ke0, ke1, kr0, kr1,
      ah0, ah1, al0, al1, bh0, bh1, bl0, bl1);
}